// Round 14
// baseline (220.220 us; speedup 1.0000x reference)
//
#include <hip/hip_runtime.h>
#include <hip/hip_bf16.h>

// GCN 2-layer encoder. CSR-gather aggregation + split-bf16 MFMA GEMMs.
// r14: BK=64 (half the barrier events per block vs r13's BK=32). h1/h2 bf16.

typedef __attribute__((ext_vector_type(4))) float f32x4;
typedef __attribute__((ext_vector_type(8))) short short8;
typedef __attribute__((ext_vector_type(8))) unsigned short u16x8;

static __device__ __forceinline__ unsigned short f2bf(float f) {
    unsigned int u = __float_as_uint(f);
    u += 0x7FFF + ((u >> 16) & 1);          // round-to-nearest-even
    return (unsigned short)(u >> 16);
}
static __device__ __forceinline__ float bf2f(unsigned short h) {
    return __uint_as_float(((unsigned int)h) << 16);
}

__global__ void deg_accum_i(const int* __restrict__ dst, int* __restrict__ deg, int E) {
    int i = blockIdx.x * blockDim.x + threadIdx.x;
    if (i < E) atomicAdd(&deg[dst[i]], 1);
}

// fused: zero degree array + convert both weights to transposed bf16 hi/lo
__global__ void prep_and_zero(const float* __restrict__ W1, const float* __restrict__ W2,
                              unsigned short* __restrict__ B1h, unsigned short* __restrict__ B1l,
                              unsigned short* __restrict__ B2h, unsigned short* __restrict__ B2l,
                              int* __restrict__ deg, int Nn,
                              int K1, int N1, int K1p, int K2, int N2, int K2p) {
    int idx = blockIdx.x * 256 + threadIdx.x;
    if (idx < Nn) deg[idx] = 0;
    int n1 = N1 * K1p;
    if (idx < n1) {
        int n = idx / K1p, k = idx - n * K1p;
        float v = (k < K1) ? W1[(size_t)k * N1 + n] : 0.f;
        unsigned short h = f2bf(v);
        B1h[idx] = h;
        B1l[idx] = f2bf(v - bf2f(h));
    } else {
        int idx2 = idx - n1;
        if (idx2 < N2 * K2p) {
            int n = idx2 / K2p, k = idx2 - n * K2p;
            float v = (k < K2) ? W2[(size_t)k * N2 + n] : 0.f;
            unsigned short h = f2bf(v);
            B2h[idx2] = h;
            B2l[idx2] = f2bf(v - bf2f(h));
        }
    }
}

// ---- hierarchical exclusive scan: deg[N] -> rp[N+1], cursor[N]; also dis = rsqrt(deg+1) ----
__global__ void scan_part(const int* __restrict__ deg, int* __restrict__ bsum, int N) {
    int tid = threadIdx.x, lane = tid & 63, wid = tid >> 6;
    int i = blockIdx.x * 256 + tid;
    int v = (i < N) ? deg[i] : 0;
#pragma unroll
    for (int off = 1; off < 64; off <<= 1) v += __shfl_xor(v, off, 64);
    __shared__ int ws[4];
    if (lane == 0) ws[wid] = v;
    __syncthreads();
    if (tid == 0) bsum[blockIdx.x] = ws[0] + ws[1] + ws[2] + ws[3];
}

__global__ __launch_bounds__(1024) void scan_top(const int* __restrict__ bsum, int nb,
                                                 int* __restrict__ boff, int* __restrict__ rp, int N) {
    __shared__ int wsum[16];
    int tid = threadIdx.x, lane = tid & 63, wid = tid >> 6;
    int v = (tid < nb) ? bsum[tid] : 0;
    int x = v;
#pragma unroll
    for (int off = 1; off < 64; off <<= 1) {
        int t = __shfl_up(x, off, 64);
        if (lane >= off) x += t;
    }
    if (lane == 63) wsum[wid] = x;
    __syncthreads();
    if (tid < 16) {
        int y = wsum[tid];
#pragma unroll
        for (int off = 1; off < 16; off <<= 1) {
            int t = __shfl_up(y, off, 16);
            if (tid >= off) y += t;
        }
        wsum[tid] = y;
    }
    __syncthreads();
    int base = wid ? wsum[wid - 1] : 0;
    if (tid < nb) boff[tid] = base + x - v;
    if (tid == 0) rp[N] = wsum[15];
}

// fused: scan finalize + cursor init + dis = rsqrt(deg+1) written in place over deg
__global__ void scan_final(int* __restrict__ deg, const int* __restrict__ boff,
                           int* __restrict__ rp, int* __restrict__ cursor, int N) {
    int tid = threadIdx.x, lane = tid & 63, wid = tid >> 6;
    int i = blockIdx.x * 256 + tid;
    int v = (i < N) ? deg[i] : 0;
    int x = v;
#pragma unroll
    for (int off = 1; off < 64; off <<= 1) {
        int t = __shfl_up(x, off, 64);
        if (lane >= off) x += t;
    }
    __shared__ int wsum[4];
    if (lane == 63) wsum[wid] = x;
    __syncthreads();
    int base = boff[blockIdx.x];
    for (int ww = 0; ww < wid; ww++) base += wsum[ww];
    int ex = base + x - v;
    if (i < N) {
        rp[i] = ex;
        cursor[i] = ex;
        ((float*)deg)[i] = rsqrtf((float)(v + 1));   // self loop adds 1
    }
}

__global__ void csr_fill(const int* __restrict__ src, const int* __restrict__ dst,
                         int* __restrict__ cursor, int* __restrict__ csr_src, int E) {
    int e = blockIdx.x * blockDim.x + threadIdx.x;
    if (e < E) {
        int pos = atomicAdd(&cursor[dst[e]], 1);
        csr_src[pos] = src[e];
    }
}

// C[M x BN] = A[M x K] @ B[K x BN], split-bf16 MFMA. BM=32, BK template (32/64).
// A fully register-preloaded; B (preconverted bf16 hi/lo [BN][Kpad]) staged via regs.
// bf16 output.
template<int BN, int BK, int KT, int WROWS, int WCOLS>
__global__ __launch_bounds__(256) void gemm_mfma(
    const float* __restrict__ A, const unsigned short* __restrict__ Bth,
    const unsigned short* __restrict__ Btl, unsigned short* __restrict__ C,
    int M, int K, int Kpad) {
    constexpr int BM = 32, STR = BK + 8;
    constexpr int MF = (BM / WROWS) / 16;
    constexpr int NF = (BN / WCOLS) / 16;
    constexpr int KS = BK / 32;              // MFMA k-steps per stage
    constexpr int AV = BK / 32;              // float4 per thread per tile (8 thr/row)
    constexpr int TPB = 256 / BN;            // threads per B row
    constexpr int SPB = BK / TPB;            // ushorts per thread per plane
    constexpr int NV = SPB / 8;              // u16x8 per thread per plane
    static_assert(NV >= 1 && AV >= 1, "staging shape");

    __shared__ unsigned short AsH[BM][STR], AsL[BM][STR];
    __shared__ unsigned short BsH[BN][STR], BsL[BN][STR];

    const int tid = threadIdx.x;
    const int lane = tid & 63;
    const int w = tid >> 6;
    const int wrow = (w / WCOLS) * (BM / WROWS);
    const int wcol = (w % WCOLS) * (BN / WCOLS);
    const int bm = blockIdx.x * BM;
    const int lrow = lane & 15;
    const int lkq = (lane >> 4) * 8;
    const int ar = tid >> 3;                 // A row (32 rows, 8 thr/row)
    const int ak = (tid & 7) * (BK / 8);     // A k-offset within tile (AV float4)
    const int bn = tid / TPB;
    const int bkoff = (tid % TPB) * SPB;

    f32x4 acc[MF][NF] = {};

    // ---- preload ALL of A for this block's 32 rows into registers ----
    float4 areg[KT][AV];
    {
        const int arow = bm + ar;
        const bool rok = arow < M;
        const float* rowp = &A[(size_t)arow * K];
#pragma unroll
        for (int kt = 0; kt < KT; kt++)
#pragma unroll
            for (int v = 0; v < AV; v++) {
                int kg = kt * BK + ak + v * 4;
                float4 x4 = make_float4(0.f, 0.f, 0.f, 0.f);
                if (rok) {
                    if (kg + 3 < K) x4 = *(const float4*)&rowp[kg];
                    else {
                        if (kg     < K) x4.x = rowp[kg];
                        if (kg + 1 < K) x4.y = rowp[kg + 1];
                        if (kg + 2 < K) x4.z = rowp[kg + 2];
                    }
                }
                areg[kt][v] = x4;
            }
    }

    u16x8 bh[NV], bl[NV];
    auto loadB = [&](int kt) {
        const size_t bo = (size_t)bn * Kpad + kt * BK + bkoff;
#pragma unroll
        for (int v = 0; v < NV; v++) {
            bh[v] = *(const u16x8*)&Bth[bo + v * 8];
            bl[v] = *(const u16x8*)&Btl[bo + v * 8];
        }
    };
    loadB(0);

    for (int kt = 0; kt < KT; kt++) {
#pragma unroll
        for (int v = 0; v < AV; v++) {
            float4 x4 = areg[kt][v];
            ushort4 h4, l4;
            h4.x = f2bf(x4.x); l4.x = f2bf(x4.x - bf2f(h4.x));
            h4.y = f2bf(x4.y); l4.y = f2bf(x4.y - bf2f(h4.y));
            h4.z = f2bf(x4.z); l4.z = f2bf(x4.z - bf2f(h4.z));
            h4.w = f2bf(x4.w); l4.w = f2bf(x4.w - bf2f(h4.w));
            *(ushort4*)&AsH[ar][ak + v * 4] = h4;
            *(ushort4*)&AsL[ar][ak + v * 4] = l4;
        }
#pragma unroll
        for (int v = 0; v < NV; v++) {
            *(u16x8*)&BsH[bn][bkoff + v * 8] = bh[v];
            *(u16x8*)&BsL[bn][bkoff + v * 8] = bl[v];
        }
        __syncthreads();
        if (kt + 1 < KT) loadB(kt + 1);      // L2-resident weight prefetch
#pragma unroll
        for (int ks = 0; ks < KS; ks++) {
            const int ko = ks * 32 + lkq;
            short8 ah[MF], al[MF], bhf[NF], blf[NF];
#pragma unroll
            for (int m = 0; m < MF; m++) {
                ah[m] = *(const short8*)&AsH[wrow + m * 16 + lrow][ko];
                al[m] = *(const short8*)&AsL[wrow + m * 16 + lrow][ko];
            }
#pragma unroll
            for (int n = 0; n < NF; n++) {
                bhf[n] = *(const short8*)&BsH[wcol + n * 16 + lrow][ko];
                blf[n] = *(const short8*)&BsL[wcol + n * 16 + lrow][ko];
            }
#pragma unroll
            for (int m = 0; m < MF; m++)
#pragma unroll
                for (int n = 0; n < NF; n++) {
                    acc[m][n] = __builtin_amdgcn_mfma_f32_16x16x32_bf16(ah[m], bhf[n], acc[m][n], 0, 0, 0);
                    acc[m][n] = __builtin_amdgcn_mfma_f32_16x16x32_bf16(al[m], bhf[n], acc[m][n], 0, 0, 0);
                    acc[m][n] = __builtin_amdgcn_mfma_f32_16x16x32_bf16(ah[m], blf[n], acc[m][n], 0, 0, 0);
                }
        }
        __syncthreads();
    }
    // store bf16: C/D layout col=lane&15, row=(lane>>4)*4+q
#pragma unroll
    for (int m = 0; m < MF; m++)
#pragma unroll
        for (int n = 0; n < NF; n++)
#pragma unroll
            for (int q = 0; q < 4; q++) {
                int row = bm + wrow + m * 16 + (lane >> 4) * 4 + q;
                int col = wcol + n * 16 + (lane & 15);
                if (row < M) C[(size_t)row * BN + col] = f2bf(acc[m][n][q]);
            }
}

// gather for F=128 (bf16 h): one wave per dst node, HALF-wave (32 lanes x 4 bf16) per edge,
// 4 accumulators per half -> 8 rows in flight. Fused self-loop + bias + relu. f32 out.
__global__ __launch_bounds__(256) void gather128(
    const int* __restrict__ rp, const int* __restrict__ csr,
    const float* __restrict__ dis, const unsigned short* __restrict__ h,
    const float* __restrict__ bias, float* __restrict__ out, int Nn) {
    int n = (blockIdx.x * 256 + threadIdx.x) >> 6;
    int lane = threadIdx.x & 63;
    if (n >= Nn) return;
    const int hh = lane >> 5;       // half id (0/1)
    const int l = lane & 31;        // 32 lanes x 4 feats
    int beg = rp[n], end = rp[n + 1];
    float4 a0 = {0,0,0,0}, a1 = {0,0,0,0}, a2 = {0,0,0,0}, a3 = {0,0,0,0};
    auto P = [&](int e, float4& a) {
        int s = csr[e];
        float w = dis[s];
        ushort4 v = *(const ushort4*)&h[(size_t)s * 128 + l * 4];
        a.x = fmaf(w, bf2f(v.x), a.x); a.y = fmaf(w, bf2f(v.y), a.y);
        a.z = fmaf(w, bf2f(v.z), a.z); a.w = fmaf(w, bf2f(v.w), a.w);
    };
    int j = beg + hh;               // this half handles indices == hh (mod 2)
    for (; j + 6 < end; j += 8) { P(j, a0); P(j + 2, a1); P(j + 4, a2); P(j + 6, a3); }
    for (; j < end; j += 2) P(j, a0);
    float4 acc;
    acc.x = (a0.x + a1.x) + (a2.x + a3.x);
    acc.y = (a0.y + a1.y) + (a2.y + a3.y);
    acc.z = (a0.z + a1.z) + (a2.z + a3.z);
    acc.w = (a0.w + a1.w) + (a2.w + a3.w);
    acc.x += __shfl_xor(acc.x, 32);
    acc.y += __shfl_xor(acc.y, 32);
    acc.z += __shfl_xor(acc.z, 32);
    acc.w += __shfl_xor(acc.w, 32);
    float dn = dis[n];
    ushort4 hv = *(const ushort4*)&h[(size_t)n * 128 + l * 4];
    float4 b4 = *(const float4*)&bias[l * 4];
    float4 o;
    o.x = fmaxf(dn * (acc.x + dn * bf2f(hv.x)) + b4.x, 0.f);
    o.y = fmaxf(dn * (acc.y + dn * bf2f(hv.y)) + b4.y, 0.f);
    o.z = fmaxf(dn * (acc.z + dn * bf2f(hv.z)) + b4.z, 0.f);
    o.w = fmaxf(dn * (acc.w + dn * bf2f(hv.w)) + b4.w, 0.f);
    if (hh == 0) *(float4*)&out[(size_t)n * 128 + l * 4] = o;
}

// gather for F=64 (bf16 h): one wave per dst node, QUARTER-wave (16 lanes x 4 bf16) per edge,
// 2 accumulators per quarter -> 8 rows in flight. Fused self-loop + bias (no relu). f32 out.
__global__ __launch_bounds__(256) void gather64(
    const int* __restrict__ rp, const int* __restrict__ csr,
    const float* __restrict__ dis, const unsigned short* __restrict__ h,
    const float* __restrict__ bias, float* __restrict__ out, int Nn) {
    int n = (blockIdx.x * 256 + threadIdx.x) >> 6;
    int lane = threadIdx.x & 63;
    if (n >= Nn) return;
    const int q = lane >> 4;        // quarter id (0..3)
    const int l = lane & 15;        // 16 lanes x 4 feats
    int beg = rp[n], end = rp[n + 1];
    float4 a0 = {0,0,0,0}, a1 = {0,0,0,0};
    auto P = [&](int e, float4& a) {
        int s = csr[e];
        float w = dis[s];
        ushort4 v = *(const ushort4*)&h[(size_t)s * 64 + l * 4];
        a.x = fmaf(w, bf2f(v.x), a.x); a.y = fmaf(w, bf2f(v.y), a.y);
        a.z = fmaf(w, bf2f(v.z), a.z); a.w = fmaf(w, bf2f(v.w), a.w);
    };
    int j = beg + q;                // this quarter handles indices == q (mod 4)
    for (; j + 4 < end; j += 8) { P(j, a0); P(j + 4, a1); }
    for (; j < end; j += 4) P(j, a0);
    float4 acc;
    acc.x = a0.x + a1.x; acc.y = a0.y + a1.y;
    acc.z = a0.z + a1.z; acc.w = a0.w + a1.w;
    acc.x += __shfl_xor(acc.x, 16); acc.x += __shfl_xor(acc.x, 32);
    acc.y += __shfl_xor(acc.y, 16); acc.y += __shfl_xor(acc.y, 32);
    acc.z += __shfl_xor(acc.z, 16); acc.z += __shfl_xor(acc.z, 32);
    acc.w += __shfl_xor(acc.w, 16); acc.w += __shfl_xor(acc.w, 32);
    float dn = dis[n];
    ushort4 hv = *(const ushort4*)&h[(size_t)n * 64 + l * 4];
    float4 b4 = *(const float4*)&bias[l * 4];
    float4 o;
    o.x = dn * (acc.x + dn * bf2f(hv.x)) + b4.x;
    o.y = dn * (acc.y + dn * bf2f(hv.y)) + b4.y;
    o.z = dn * (acc.z + dn * bf2f(hv.z)) + b4.z;
    o.w = dn * (acc.w + dn * bf2f(hv.w)) + b4.w;
    if (q == 0) *(float4*)&out[(size_t)n * 64 + l * 4] = o;
}

extern "C" void kernel_launch(void* const* d_in, const int* in_sizes, int n_in,
                              void* d_out, int out_size, void* d_ws, size_t ws_size,
                              hipStream_t stream) {
    const float* x  = (const float*)d_in[0];
    const int*   ei = (const int*)d_in[1];
    const float* W1 = (const float*)d_in[2];
    const float* b1 = (const float*)d_in[3];
    const float* W2 = (const float*)d_in[4];
    const float* b2 = (const float*)d_in[5];

    const int IN = 500, H = 128, OUT = 64;
    const int Nn = in_sizes[0] / IN;     // 50000
    const int E  = in_sizes[1] / 2;      // 800000
    const int* src  = ei;
    const int* dstp = ei + E;

    const int Npad = ((Nn + 63) / 64) * 64;
    const int nb   = (Nn + 255) / 256;
    const int K1p  = 512, K2p = 128;

    // workspace layout (int units)
    int*   degdis  = (int*)d_ws;                 // N: int deg -> float dis in place
    int*   rp      = degdis + Npad;              // N+1
    int*   bsum    = rp + Npad + 64;             // 1024
    int*   boff    = bsum + 1024;                // 1024
    int*   cursor  = boff + 1024;                // N
    int*   csr_src = cursor + Npad;              // E
    unsigned short* Bt1h = (unsigned short*)(csr_src + ((E + 63) / 64) * 64);  // 128*512
    unsigned short* Bt1l = Bt1h + H * K1p;
    unsigned short* Bt2h = Bt1l + H * K1p;       // 64*128
    unsigned short* Bt2l = Bt2h + OUT * K2p;
    unsigned short* h1u  = Bt2l + OUT * K2p;     // N*128 bf16
    float* agg1    = (float*)(h1u + (size_t)Nn * H);  // N*128 f32
    unsigned short* h2u  = h1u;                  // reuse after layer-1 gather
    float* dis     = (float*)degdis;
    float* out     = (float*)d_out;

    // ---- degree zero + weight prep (single launch) ----
    prep_and_zero<<<(H * K1p + OUT * K2p + 255) / 256, 256, 0, stream>>>(
        W1, W2, Bt1h, Bt1l, Bt2h, Bt2l, degdis, Nn, IN, H, K1p, H, OUT, K2p);
    deg_accum_i<<<(E + 255) / 256, 256, 0, stream>>>(dstp, degdis, E);
    scan_part<<<nb, 256, 0, stream>>>(degdis, bsum, Nn);
    scan_top<<<1, 1024, 0, stream>>>(bsum, nb, boff, rp, Nn);
    scan_final<<<nb, 256, 0, stream>>>(degdis, boff, rp, cursor, Nn);
    csr_fill<<<(E + 255) / 256, 256, 0, stream>>>(src, dstp, cursor, csr_src, E);

    // ---- layer 1: BK=64, KT=8 ----
    gemm_mfma<128, 64, 8, 2, 2><<<(Nn + 31) / 32, 256, 0, stream>>>(x, Bt1h, Bt1l, h1u, Nn, IN, K1p);
    gather128<<<(Nn + 3) / 4, 256, 0, stream>>>(rp, csr_src, dis, h1u, b1, agg1, Nn);

    // ---- layer 2: BK=64, KT=2 ----
    gemm_mfma<64, 64, 2, 2, 2><<<(Nn + 31) / 32, 256, 0, stream>>>(agg1, Bt2h, Bt2l, h2u, Nn, H, K2p);
    gather64<<<(Nn + 3) / 4, 256, 0, stream>>>(rp, csr_src, dis, h2u, b2, out, Nn);
}

// Round 15
// 217.091 us; speedup vs baseline: 1.0144x; 1.0144x over previous
//
#include <hip/hip_runtime.h>
#include <hip/hip_bf16.h>

// GCN 2-layer encoder. CSR-gather aggregation + split-bf16 MFMA GEMMs.
// r15: GEMMs restructured on the m97 pattern — global_load_lds(16B) staging into
// slot-major LDS images, double-buffered, 1 barrier/K-step. B pre-tiled per K-step.

typedef __attribute__((ext_vector_type(4))) float f32x4;
typedef __attribute__((ext_vector_type(8))) short short8;

static __device__ __forceinline__ unsigned short f2bf(float f) {
    unsigned int u = __float_as_uint(f);
    u += 0x7FFF + ((u >> 16) & 1);          // round-to-nearest-even
    return (unsigned short)(u >> 16);
}
static __device__ __forceinline__ float bf2f(unsigned short h) {
    return __uint_as_float(((unsigned int)h) << 16);
}

static __device__ __forceinline__ void glds16(const void* g, void* l) {
    __builtin_amdgcn_global_load_lds(
        (const __attribute__((address_space(1))) void*)g,
        (__attribute__((address_space(3))) void*)l, 16, 0, 0);
}

__global__ void deg_accum_i(const int* __restrict__ dst, int* __restrict__ deg, int E) {
    int i = blockIdx.x * blockDim.x + threadIdx.x;
    if (i < E) atomicAdd(&deg[dst[i]], 1);
}

// fused: zero degree + build per-K-step B images (bf16 hi/lo, [kt][plane][slot][col] 16B chunks)
__global__ void prep_imgs(const float* __restrict__ W1, const float* __restrict__ W2,
                          unsigned short* __restrict__ I1, unsigned short* __restrict__ I2,
                          int* __restrict__ deg, int Nn) {
    int idx = blockIdx.x * 256 + threadIdx.x;
    if (idx < Nn) deg[idx] = 0;
    const int total1 = 16 * 1024;            // 16 kt x 2 pl x 4 slot x 128 col
    if (idx < total1) {
        int kt = idx >> 10, pl = (idx >> 9) & 1, slot = (idx >> 7) & 3, col = idx & 127;
        int k0 = kt * 32 + slot * 8;
#pragma unroll
        for (int j = 0; j < 8; j++) {
            int k = k0 + j;
            float v = (k < 500) ? W1[(size_t)k * 128 + col] : 0.f;
            unsigned short h = f2bf(v);
            I1[(size_t)idx * 8 + j] = pl ? f2bf(v - bf2f(h)) : h;
        }
    } else if (idx < total1 + 2048) {        // 4 kt x 2 pl x 4 slot x 64 col
        int i2 = idx - total1;
        int kt = i2 >> 9, pl = (i2 >> 8) & 1, slot = (i2 >> 6) & 3, col = i2 & 63;
        int k0 = kt * 32 + slot * 8;
#pragma unroll
        for (int j = 0; j < 8; j++) {
            float v = W2[(size_t)(k0 + j) * 64 + col];
            unsigned short h = f2bf(v);
            I2[(size_t)i2 * 8 + j] = pl ? f2bf(v - bf2f(h)) : h;
        }
    }
}

// ---- hierarchical exclusive scan ----
__global__ void scan_part(const int* __restrict__ deg, int* __restrict__ bsum, int N) {
    int tid = threadIdx.x, lane = tid & 63, wid = tid >> 6;
    int i = blockIdx.x * 256 + tid;
    int v = (i < N) ? deg[i] : 0;
#pragma unroll
    for (int off = 1; off < 64; off <<= 1) v += __shfl_xor(v, off, 64);
    __shared__ int ws[4];
    if (lane == 0) ws[wid] = v;
    __syncthreads();
    if (tid == 0) bsum[blockIdx.x] = ws[0] + ws[1] + ws[2] + ws[3];
}

__global__ __launch_bounds__(1024) void scan_top(const int* __restrict__ bsum, int nb,
                                                 int* __restrict__ boff, int* __restrict__ rp, int N) {
    __shared__ int wsum[16];
    int tid = threadIdx.x, lane = tid & 63, wid = tid >> 6;
    int v = (tid < nb) ? bsum[tid] : 0;
    int x = v;
#pragma unroll
    for (int off = 1; off < 64; off <<= 1) {
        int t = __shfl_up(x, off, 64);
        if (lane >= off) x += t;
    }
    if (lane == 63) wsum[wid] = x;
    __syncthreads();
    if (tid < 16) {
        int y = wsum[tid];
#pragma unroll
        for (int off = 1; off < 16; off <<= 1) {
            int t = __shfl_up(y, off, 16);
            if (tid >= off) y += t;
        }
        wsum[tid] = y;
    }
    __syncthreads();
    int base = wid ? wsum[wid - 1] : 0;
    if (tid < nb) boff[tid] = base + x - v;
    if (tid == 0) rp[N] = wsum[15];
}

__global__ void scan_final(int* __restrict__ deg, const int* __restrict__ boff,
                           int* __restrict__ rp, int* __restrict__ cursor, int N) {
    int tid = threadIdx.x, lane = tid & 63, wid = tid >> 6;
    int i = blockIdx.x * 256 + tid;
    int v = (i < N) ? deg[i] : 0;
    int x = v;
#pragma unroll
    for (int off = 1; off < 64; off <<= 1) {
        int t = __shfl_up(x, off, 64);
        if (lane >= off) x += t;
    }
    __shared__ int wsum[4];
    if (lane == 63) wsum[wid] = x;
    __syncthreads();
    int base = boff[blockIdx.x];
    for (int ww = 0; ww < wid; ww++) base += wsum[ww];
    int ex = base + x - v;
    if (i < N) {
        rp[i] = ex;
        cursor[i] = ex;
        ((float*)deg)[i] = rsqrtf((float)(v + 1));
    }
}

__global__ void csr_fill(const int* __restrict__ src, const int* __restrict__ dst,
                         int* __restrict__ cursor, int* __restrict__ csr_src, int E) {
    int e = blockIdx.x * blockDim.x + threadIdx.x;
    if (e < E) {
        int pos = atomicAdd(&cursor[dst[e]], 1);
        csr_src[pos] = src[e];
    }
}

// C[M x BN] = A[M x K] @ B, split-bf16 MFMA, m97-style global_load_lds staging.
// BM=64, BK=32, 4 waves (2x2), wave tile 32 x BN/2. Double-buffered LDS.
// A: f32 slot-major image (8 KB/step, glds from row-major A, rows clamped).
// B: pre-tiled bf16 hi/lo step-images (linear copy). KFULL<KT => last tile reg-staged.
template<int BN, int KT, int KFULL>
__global__ __launch_bounds__(256) void gemm_glds(
    const float* __restrict__ A, const unsigned char* __restrict__ Wimg,
    unsigned short* __restrict__ C, int M, int K) {
    constexpr int ABYTES = 64 * 32 * 4;          // 8192
    constexpr int BBYTES = BN * 32 * 2 * 2;      // 16384 (BN=128) / 8192 (BN=64)
    constexpr int STEP = ABYTES + BBYTES;
    constexpr int AINST = ABYTES / 1024;         // 8
    constexpr int BINST = BBYTES / 1024;         // 16 / 8
    constexpr int IPW = (AINST + BINST) / 4;     // 6 / 4
    constexpr int BIPW = BINST / 4;              // 4 / 2
    constexpr int NF = BN / 32;                  // 4 / 2

    __shared__ unsigned char smem[2][STEP];

    const int tid = threadIdx.x, lane = tid & 63, w = tid >> 6;
    const int lrow = lane & 15, lq = lane >> 4;
    const int wrow = (w >> 1) * 32;
    const int wcol = (w & 1) * (BN / 2);
    const int bm = blockIdx.x * 64;

    f32x4 acc[2][NF] = {};

    // partial-tile A regs (issued in prologue; drained by first barrier)
    float pr[8];
    if constexpr (KFULL < KT) {
        const int prow = tid >> 2, pk = (tid & 3) * 8;
        const int grow = bm + prow;
#pragma unroll
        for (int j = 0; j < 8; j++) {
            int k = KFULL * 32 + pk + j;
            pr[j] = (grow < M && k < K) ? A[(size_t)grow * K + k] : 0.f;
        }
    }

    auto STAGE = [&](int kt, int buf) {          // full stage: A + B
        unsigned char* base = &smem[buf][0];
#pragma unroll
        for (int j = 0; j < IPW; j++) {
            int g = w * IPW + j;
            if (g < AINST) {
                int srow = bm + lane; if (srow >= M) srow = M - 1;
                glds16(A + (size_t)srow * K + kt * 32 + g * 4, base + g * 1024);
            } else {
                int b = g - AINST;
                glds16(Wimg + (size_t)kt * BBYTES + (size_t)b * 1024 + lane * 16,
                       base + ABYTES + b * 1024);
            }
        }
    };
    auto STAGE_B = [&](int kt, int buf) {        // B only (partial-tile step)
        unsigned char* base = &smem[buf][0];
#pragma unroll
        for (int j = 0; j < BIPW; j++) {
            int b = w * BIPW + j;
            glds16(Wimg + (size_t)kt * BBYTES + (size_t)b * 1024 + lane * 16,
                   base + ABYTES + b * 1024);
        }
    };
    auto REGWRITE = [&](int buf) {               // write pr[] as the A-tile
        const int prow = tid >> 2, pk = (tid & 3) * 8;
        unsigned char* base = &smem[buf][0];
        int s0 = pk >> 2;
        *(float4*)(base + s0 * 1024 + prow * 16) = make_float4(pr[0], pr[1], pr[2], pr[3]);
        *(float4*)(base + (s0 + 1) * 1024 + prow * 16) = make_float4(pr[4], pr[5], pr[6], pr[7]);
    };
    auto COMPUTE = [&](int buf) {
        const unsigned char* base = &smem[buf][0];
        short8 ah[2], al[2];
#pragma unroll
        for (int m = 0; m < 2; m++) {
            int r = wrow + m * 16 + lrow;
            float4 f0 = *(const float4*)(base + (lq * 2) * 1024 + r * 16);
            float4 f1 = *(const float4*)(base + (lq * 2 + 1) * 1024 + r * 16);
            float fv[8] = {f0.x, f0.y, f0.z, f0.w, f1.x, f1.y, f1.z, f1.w};
#pragma unroll
            for (int e = 0; e < 8; e++) {
                unsigned short hu = f2bf(fv[e]);
                ah[m][e] = (short)hu;
                al[m][e] = (short)f2bf(fv[e] - bf2f(hu));
            }
        }
        short8 bh[NF], bl[NF];
#pragma unroll
        for (int n = 0; n < NF; n++) {
            int c = wcol + n * 16 + lrow;
            bh[n] = *(const short8*)(base + ABYTES + lq * (BN * 16) + c * 16);
            bl[n] = *(const short8*)(base + ABYTES + BBYTES / 2 + lq * (BN * 16) + c * 16);
        }
#pragma unroll
        for (int m = 0; m < 2; m++)
#pragma unroll
            for (int n = 0; n < NF; n++) {
                acc[m][n] = __builtin_amdgcn_mfma_f32_16x16x32_bf16(ah[m], bh[n], acc[m][n], 0, 0, 0);
                acc[m][n] = __builtin_amdgcn_mfma_f32_16x16x32_bf16(al[m], bh[n], acc[m][n], 0, 0, 0);
                acc[m][n] = __builtin_amdgcn_mfma_f32_16x16x32_bf16(ah[m], bl[n], acc[m][n], 0, 0, 0);
            }
    };

    STAGE(0, 0);
    __syncthreads();
    int cur = 0;
    for (int kt = 0; kt < KT; kt++) {
        if (kt + 1 < KT) {
            if constexpr (KFULL < KT) {
                if (kt + 1 == KFULL) { STAGE_B(kt + 1, cur ^ 1); REGWRITE(cur ^ 1); }
                else STAGE(kt + 1, cur ^ 1);
            } else {
                STAGE(kt + 1, cur ^ 1);
            }
        }
        COMPUTE(cur);
        __syncthreads();
        cur ^= 1;
    }

    // store bf16: C/D layout col=lane&15, row=(lane>>4)*4+q
#pragma unroll
    for (int m = 0; m < 2; m++)
#pragma unroll
        for (int n = 0; n < NF; n++)
#pragma unroll
            for (int q = 0; q < 4; q++) {
                int row = bm + wrow + m * 16 + (lane >> 4) * 4 + q;
                int col = wcol + n * 16 + (lane & 15);
                if (row < M) C[(size_t)row * BN + col] = f2bf(acc[m][n][q]);
            }
}

// gather for F=128 (bf16 h): half-wave x float4-of-bf16 per edge, 8 rows in flight.
__global__ __launch_bounds__(256) void gather128(
    const int* __restrict__ rp, const int* __restrict__ csr,
    const float* __restrict__ dis, const unsigned short* __restrict__ h,
    const float* __restrict__ bias, float* __restrict__ out, int Nn) {
    int n = (blockIdx.x * 256 + threadIdx.x) >> 6;
    int lane = threadIdx.x & 63;
    if (n >= Nn) return;
    const int hh = lane >> 5;
    const int l = lane & 31;
    int beg = rp[n], end = rp[n + 1];
    float4 a0 = {0,0,0,0}, a1 = {0,0,0,0}, a2 = {0,0,0,0}, a3 = {0,0,0,0};
    auto P = [&](int e, float4& a) {
        int s = csr[e];
        float w = dis[s];
        ushort4 v = *(const ushort4*)&h[(size_t)s * 128 + l * 4];
        a.x = fmaf(w, bf2f(v.x), a.x); a.y = fmaf(w, bf2f(v.y), a.y);
        a.z = fmaf(w, bf2f(v.z), a.z); a.w = fmaf(w, bf2f(v.w), a.w);
    };
    int j = beg + hh;
    for (; j + 6 < end; j += 8) { P(j, a0); P(j + 2, a1); P(j + 4, a2); P(j + 6, a3); }
    for (; j < end; j += 2) P(j, a0);
    float4 acc;
    acc.x = (a0.x + a1.x) + (a2.x + a3.x);
    acc.y = (a0.y + a1.y) + (a2.y + a3.y);
    acc.z = (a0.z + a1.z) + (a2.z + a3.z);
    acc.w = (a0.w + a1.w) + (a2.w + a3.w);
    acc.x += __shfl_xor(acc.x, 32);
    acc.y += __shfl_xor(acc.y, 32);
    acc.z += __shfl_xor(acc.z, 32);
    acc.w += __shfl_xor(acc.w, 32);
    float dn = dis[n];
    ushort4 hv = *(const ushort4*)&h[(size_t)n * 128 + l * 4];
    float4 b4 = *(const float4*)&bias[l * 4];
    float4 o;
    o.x = fmaxf(dn * (acc.x + dn * bf2f(hv.x)) + b4.x, 0.f);
    o.y = fmaxf(dn * (acc.y + dn * bf2f(hv.y)) + b4.y, 0.f);
    o.z = fmaxf(dn * (acc.z + dn * bf2f(hv.z)) + b4.z, 0.f);
    o.w = fmaxf(dn * (acc.w + dn * bf2f(hv.w)) + b4.w, 0.f);
    if (hh == 0) *(float4*)&out[(size_t)n * 128 + l * 4] = o;
}

// gather for F=64 (bf16 h): quarter-wave x float4-of-bf16 per edge, 8 rows in flight.
__global__ __launch_bounds__(256) void gather64(
    const int* __restrict__ rp, const int* __restrict__ csr,
    const float* __restrict__ dis, const unsigned short* __restrict__ h,
    const float* __restrict__ bias, float* __restrict__ out, int Nn) {
    int n = (blockIdx.x * 256 + threadIdx.x) >> 6;
    int lane = threadIdx.x & 63;
    if (n >= Nn) return;
    const int q = lane >> 4;
    const int l = lane & 15;
    int beg = rp[n], end = rp[n + 1];
    float4 a0 = {0,0,0,0}, a1 = {0,0,0,0};
    auto P = [&](int e, float4& a) {
        int s = csr[e];
        float w = dis[s];
        ushort4 v = *(const ushort4*)&h[(size_t)s * 64 + l * 4];
        a.x = fmaf(w, bf2f(v.x), a.x); a.y = fmaf(w, bf2f(v.y), a.y);
        a.z = fmaf(w, bf2f(v.z), a.z); a.w = fmaf(w, bf2f(v.w), a.w);
    };
    int j = beg + q;
    for (; j + 4 < end; j += 8) { P(j, a0); P(j + 4, a1); }
    for (; j < end; j += 4) P(j, a0);
    float4 acc;
    acc.x = a0.x + a1.x; acc.y = a0.y + a1.y;
    acc.z = a0.z + a1.z; acc.w = a0.w + a1.w;
    acc.x += __shfl_xor(acc.x, 16); acc.x += __shfl_xor(acc.x, 32);
    acc.y += __shfl_xor(acc.y, 16); acc.y += __shfl_xor(acc.y, 32);
    acc.z += __shfl_xor(acc.z, 16); acc.z += __shfl_xor(acc.z, 32);
    acc.w += __shfl_xor(acc.w, 16); acc.w += __shfl_xor(acc.w, 32);
    float dn = dis[n];
    ushort4 hv = *(const ushort4*)&h[(size_t)n * 64 + l * 4];
    float4 b4 = *(const float4*)&bias[l * 4];
    float4 o;
    o.x = dn * (acc.x + dn * bf2f(hv.x)) + b4.x;
    o.y = dn * (acc.y + dn * bf2f(hv.y)) + b4.y;
    o.z = dn * (acc.z + dn * bf2f(hv.z)) + b4.z;
    o.w = dn * (acc.w + dn * bf2f(hv.w)) + b4.w;
    if (q == 0) *(float4*)&out[(size_t)n * 64 + l * 4] = o;
}

extern "C" void kernel_launch(void* const* d_in, const int* in_sizes, int n_in,
                              void* d_out, int out_size, void* d_ws, size_t ws_size,
                              hipStream_t stream) {
    const float* x  = (const float*)d_in[0];
    const int*   ei = (const int*)d_in[1];
    const float* W1 = (const float*)d_in[2];
    const float* b1 = (const float*)d_in[3];
    const float* W2 = (const float*)d_in[4];
    const float* b2 = (const float*)d_in[5];

    const int IN = 500, H = 128, OUT = 64;
    const int Nn = in_sizes[0] / IN;     // 50000
    const int E  = in_sizes[1] / 2;      // 800000
    const int* src  = ei;
    const int* dstp = ei + E;

    const int Npad = ((Nn + 63) / 64) * 64;
    const int nb   = (Nn + 255) / 256;

    // workspace layout (int units)
    int*   degdis  = (int*)d_ws;                 // N: int deg -> float dis in place
    int*   rp      = degdis + Npad;              // N+1
    int*   bsum    = rp + Npad + 64;             // 1024
    int*   boff    = bsum + 1024;                // 1024
    int*   cursor  = boff + 1024;                // N
    int*   csr_src = cursor + Npad;              // E
    unsigned short* I1 = (unsigned short*)(csr_src + ((E + 63) / 64) * 64);  // 16 x 16KB
    unsigned short* I2 = I1 + 16 * 8192;         // 4 x 8KB
    unsigned short* h1u = I2 + 4 * 4096;         // Npad x 128 bf16
    float* agg1    = (float*)(h1u + (size_t)Npad * H);  // Npad x 128 f32
    unsigned short* h2u = h1u;                   // reuse after layer-1 gather
    float* dis     = (float*)degdis;
    float* out     = (float*)d_out;

    // ---- degree zero + B-image prep (single launch) ----
    prep_imgs<<<(Nn + 255) / 256, 256, 0, stream>>>(W1, W2, I1, I2, degdis, Nn);
    deg_accum_i<<<(E + 255) / 256, 256, 0, stream>>>(dstp, degdis, E);
    scan_part<<<nb, 256, 0, stream>>>(degdis, bsum, Nn);
    scan_top<<<1, 1024, 0, stream>>>(bsum, nb, boff, rp, Nn);
    scan_final<<<nb, 256, 0, stream>>>(degdis, boff, rp, cursor, Nn);
    csr_fill<<<(E + 255) / 256, 256, 0, stream>>>(src, dstp, cursor, csr_src, E);

    // ---- layer 1: KT=16 (kt 15 partial, reg-staged A) ----
    gemm_glds<128, 16, 15><<<(Nn + 63) / 64, 256, 0, stream>>>(
        x, (const unsigned char*)I1, h1u, Nn, IN);
    gather128<<<(Nn + 3) / 4, 256, 0, stream>>>(rp, csr_src, dis, h1u, b1, agg1, Nn);

    // ---- layer 2: KT=4, all full ----
    gemm_glds<64, 4, 4><<<(Nn + 63) / 64, 256, 0, stream>>>(
        agg1, (const unsigned char*)I2, h2u, Nn, H);
    gather64<<<(Nn + 3) / 4, 256, 0, stream>>>(rp, csr_src, dis, h2u, b2, out, Nn);
}

// Round 16
// 185.649 us; speedup vs baseline: 1.1862x; 1.1694x over previous
//
#include <hip/hip_runtime.h>
#include <hip/hip_bf16.h>

// GCN 2-layer encoder. CSR-gather aggregation + split-bf16 MFMA GEMMs.
// r16: gemm1 and csr_fill fused into one fat kernel (1:4 block stripes) for CU-level
// concurrency; WR=4 wave layout de-duplicates A-conversion. glds staging as r15.

typedef __attribute__((ext_vector_type(4))) float f32x4;
typedef __attribute__((ext_vector_type(8))) short short8;

static __device__ __forceinline__ unsigned short f2bf(float f) {
    unsigned int u = __float_as_uint(f);
    u += 0x7FFF + ((u >> 16) & 1);          // round-to-nearest-even
    return (unsigned short)(u >> 16);
}
static __device__ __forceinline__ float bf2f(unsigned short h) {
    return __uint_as_float(((unsigned int)h) << 16);
}

static __device__ __forceinline__ void glds16(const void* g, void* l) {
    __builtin_amdgcn_global_load_lds(
        (const __attribute__((address_space(1))) void*)g,
        (__attribute__((address_space(3))) void*)l, 16, 0, 0);
}

__global__ void deg_accum_i(const int* __restrict__ dst, int* __restrict__ deg, int E) {
    int i = blockIdx.x * blockDim.x + threadIdx.x;
    if (i < E) atomicAdd(&deg[dst[i]], 1);
}

// fused: zero degree + build per-K-step B images (bf16 hi/lo, [kt][plane][slot][col] 16B chunks)
__global__ void prep_imgs(const float* __restrict__ W1, const float* __restrict__ W2,
                          unsigned short* __restrict__ I1, unsigned short* __restrict__ I2,
                          int* __restrict__ deg, int Nn) {
    int idx = blockIdx.x * 256 + threadIdx.x;
    if (idx < Nn) deg[idx] = 0;
    const int total1 = 16 * 1024;            // 16 kt x 2 pl x 4 slot x 128 col
    if (idx < total1) {
        int kt = idx >> 10, pl = (idx >> 9) & 1, slot = (idx >> 7) & 3, col = idx & 127;
        int k0 = kt * 32 + slot * 8;
#pragma unroll
        for (int j = 0; j < 8; j++) {
            int k = k0 + j;
            float v = (k < 500) ? W1[(size_t)k * 128 + col] : 0.f;
            unsigned short h = f2bf(v);
            I1[(size_t)idx * 8 + j] = pl ? f2bf(v - bf2f(h)) : h;
        }
    } else if (idx < total1 + 2048) {        // 4 kt x 2 pl x 4 slot x 64 col
        int i2 = idx - total1;
        int kt = i2 >> 9, pl = (i2 >> 8) & 1, slot = (i2 >> 6) & 3, col = i2 & 63;
        int k0 = kt * 32 + slot * 8;
#pragma unroll
        for (int j = 0; j < 8; j++) {
            float v = W2[(size_t)(k0 + j) * 64 + col];
            unsigned short h = f2bf(v);
            I2[(size_t)i2 * 8 + j] = pl ? f2bf(v - bf2f(h)) : h;
        }
    }
}

// ---- hierarchical exclusive scan ----
__global__ void scan_part(const int* __restrict__ deg, int* __restrict__ bsum, int N) {
    int tid = threadIdx.x, lane = tid & 63, wid = tid >> 6;
    int i = blockIdx.x * 256 + tid;
    int v = (i < N) ? deg[i] : 0;
#pragma unroll
    for (int off = 1; off < 64; off <<= 1) v += __shfl_xor(v, off, 64);
    __shared__ int ws[4];
    if (lane == 0) ws[wid] = v;
    __syncthreads();
    if (tid == 0) bsum[blockIdx.x] = ws[0] + ws[1] + ws[2] + ws[3];
}

__global__ __launch_bounds__(1024) void scan_top(const int* __restrict__ bsum, int nb,
                                                 int* __restrict__ boff, int* __restrict__ rp, int N) {
    __shared__ int wsum[16];
    int tid = threadIdx.x, lane = tid & 63, wid = tid >> 6;
    int v = (tid < nb) ? bsum[tid] : 0;
    int x = v;
#pragma unroll
    for (int off = 1; off < 64; off <<= 1) {
        int t = __shfl_up(x, off, 64);
        if (lane >= off) x += t;
    }
    if (lane == 63) wsum[wid] = x;
    __syncthreads();
    if (tid < 16) {
        int y = wsum[tid];
#pragma unroll
        for (int off = 1; off < 16; off <<= 1) {
            int t = __shfl_up(y, off, 16);
            if (tid >= off) y += t;
        }
        wsum[tid] = y;
    }
    __syncthreads();
    int base = wid ? wsum[wid - 1] : 0;
    if (tid < nb) boff[tid] = base + x - v;
    if (tid == 0) rp[N] = wsum[15];
}

__global__ void scan_final(int* __restrict__ deg, const int* __restrict__ boff,
                           int* __restrict__ rp, int* __restrict__ cursor, int N) {
    int tid = threadIdx.x, lane = tid & 63, wid = tid >> 6;
    int i = blockIdx.x * 256 + tid;
    int v = (i < N) ? deg[i] : 0;
    int x = v;
#pragma unroll
    for (int off = 1; off < 64; off <<= 1) {
        int t = __shfl_up(x, off, 64);
        if (lane >= off) x += t;
    }
    __shared__ int wsum[4];
    if (lane == 63) wsum[wid] = x;
    __syncthreads();
    int base = boff[blockIdx.x];
    for (int ww = 0; ww < wid; ww++) base += wsum[ww];
    int ex = base + x - v;
    if (i < N) {
        rp[i] = ex;
        cursor[i] = ex;
        ((float*)deg)[i] = rsqrtf((float)(v + 1));
    }
}

// gemm body: C[M x BN] = A[M x K] @ B, split-bf16 MFMA, glds staging, WR=4 (wave tile 16xBN).
template<int BN, int KT, int KFULL>
__device__ __forceinline__ void gemm_body(
    int bid, unsigned char* sm,
    const float* __restrict__ A, const unsigned char* __restrict__ Wimg,
    unsigned short* __restrict__ C, int M, int K) {
    constexpr int ABYTES = 64 * 32 * 4;          // 8192
    constexpr int BBYTES = BN * 128;             // 16384 (BN=128) / 8192 (BN=64)
    constexpr int STEP = ABYTES + BBYTES;
    constexpr int AINST = ABYTES / 1024;         // 8
    constexpr int BINST = BBYTES / 1024;         // 16 / 8
    constexpr int IPW = (AINST + BINST) / 4;     // 6 / 4
    constexpr int BIPW = BINST / 4;              // 4 / 2
    constexpr int NF = BN / 16;                  // 8 / 4

    const int tid = threadIdx.x, lane = tid & 63, w = tid >> 6;
    const int lrow = lane & 15, lq = lane >> 4;
    const int bm = bid * 64;

    f32x4 acc[NF] = {};

    float pr[8];
    if constexpr (KFULL < KT) {
        const int prow = tid >> 2, pk = (tid & 3) * 8;
        const int grow = bm + prow;
#pragma unroll
        for (int j = 0; j < 8; j++) {
            int k = KFULL * 32 + pk + j;
            pr[j] = (grow < M && k < K) ? A[(size_t)grow * K + k] : 0.f;
        }
    }

    auto STAGE = [&](int kt, int buf) {
        unsigned char* base = sm + buf * STEP;
#pragma unroll
        for (int j = 0; j < IPW; j++) {
            int g = w * IPW + j;
            if (g < AINST) {
                int srow = bm + lane; if (srow >= M) srow = M - 1;
                glds16(A + (size_t)srow * K + kt * 32 + g * 4, base + g * 1024);
            } else {
                int b = g - AINST;
                glds16(Wimg + (size_t)kt * BBYTES + (size_t)b * 1024 + lane * 16,
                       base + ABYTES + b * 1024);
            }
        }
    };
    auto STAGE_B = [&](int kt, int buf) {
        unsigned char* base = sm + buf * STEP;
#pragma unroll
        for (int j = 0; j < BIPW; j++) {
            int b = w * BIPW + j;
            glds16(Wimg + (size_t)kt * BBYTES + (size_t)b * 1024 + lane * 16,
                   base + ABYTES + b * 1024);
        }
    };
    auto REGWRITE = [&](int buf) {
        const int prow = tid >> 2, pk = (tid & 3) * 8;
        unsigned char* base = sm + buf * STEP;
        int s0 = pk >> 2;
        *(float4*)(base + s0 * 1024 + prow * 16) = make_float4(pr[0], pr[1], pr[2], pr[3]);
        *(float4*)(base + (s0 + 1) * 1024 + prow * 16) = make_float4(pr[4], pr[5], pr[6], pr[7]);
    };
    auto COMPUTE = [&](int buf) {
        const unsigned char* base = sm + buf * STEP;
        short8 ah, al;
        {
            int r = w * 16 + lrow;
            float4 f0 = *(const float4*)(base + (lq * 2) * 1024 + r * 16);
            float4 f1 = *(const float4*)(base + (lq * 2 + 1) * 1024 + r * 16);
            float fv[8] = {f0.x, f0.y, f0.z, f0.w, f1.x, f1.y, f1.z, f1.w};
#pragma unroll
            for (int e = 0; e < 8; e++) {
                unsigned short hu = f2bf(fv[e]);
                ah[e] = (short)hu;
                al[e] = (short)f2bf(fv[e] - bf2f(hu));
            }
        }
        short8 bh[NF], bl[NF];
#pragma unroll
        for (int n = 0; n < NF; n++) {
            int c = n * 16 + lrow;
            bh[n] = *(const short8*)(base + ABYTES + lq * (BN * 16) + c * 16);
            bl[n] = *(const short8*)(base + ABYTES + BBYTES / 2 + lq * (BN * 16) + c * 16);
        }
#pragma unroll
        for (int n = 0; n < NF; n++) {
            acc[n] = __builtin_amdgcn_mfma_f32_16x16x32_bf16(ah, bh[n], acc[n], 0, 0, 0);
            acc[n] = __builtin_amdgcn_mfma_f32_16x16x32_bf16(al, bh[n], acc[n], 0, 0, 0);
            acc[n] = __builtin_amdgcn_mfma_f32_16x16x32_bf16(ah, bl[n], acc[n], 0, 0, 0);
        }
    };

    STAGE(0, 0);
    __syncthreads();
    int cur = 0;
    for (int kt = 0; kt < KT; kt++) {
        if (kt + 1 < KT) {
            if constexpr (KFULL < KT) {
                if (kt + 1 == KFULL) { STAGE_B(kt + 1, cur ^ 1); REGWRITE(cur ^ 1); }
                else STAGE(kt + 1, cur ^ 1);
            } else {
                STAGE(kt + 1, cur ^ 1);
            }
        }
        COMPUTE(cur);
        __syncthreads();
        cur ^= 1;
    }

#pragma unroll
    for (int n = 0; n < NF; n++)
#pragma unroll
        for (int q = 0; q < 4; q++) {
            int row = bm + w * 16 + (lane >> 4) * 4 + q;
            int col = n * 16 + (lane & 15);
            if (row < M) C[(size_t)row * BN + col] = f2bf(acc[n][q]);
        }
}

// plain gemm kernel (layer 2)
template<int BN, int KT, int KFULL>
__global__ __launch_bounds__(256) void gemm_glds(
    const float* __restrict__ A, const unsigned char* __restrict__ Wimg,
    unsigned short* __restrict__ C, int M, int K) {
    __shared__ unsigned char sm[2 * (8192 + BN * 128)];
    gemm_body<BN, KT, KFULL>(blockIdx.x, sm, A, Wimg, C, M, K);
}

// FAT: gemm1 (stripe pos 0) || csr_fill (stripe pos 1..4)
template<int BN, int KT, int KFULL>
__global__ __launch_bounds__(256) void fat_gemm_csr(
    const float* __restrict__ A, const unsigned char* __restrict__ Wimg,
    unsigned short* __restrict__ C, int M, int K,
    const int* __restrict__ src, const int* __restrict__ dst,
    int* __restrict__ cursor, int* __restrict__ csr_src, int E,
    int ngemm, int ncsr) {
    __shared__ unsigned char sm[2 * (8192 + BN * 128)];
    const int bid = blockIdx.x;
    const int stripe = bid / 5, pos = bid % 5;
    if (pos == 0) {
        if (stripe < ngemm)
            gemm_body<BN, KT, KFULL>(stripe, sm, A, Wimg, C, M, K);
    } else {
        int c = stripe * 4 + pos - 1;
        if (c < ncsr) {
            int e = c * 256 + threadIdx.x;
            if (e < E) {
                int p = atomicAdd(&cursor[dst[e]], 1);
                csr_src[p] = src[e];
            }
        }
    }
}

// gather for F=128 (bf16 h): half-wave per edge, 8 rows in flight.
__global__ __launch_bounds__(256) void gather128(
    const int* __restrict__ rp, const int* __restrict__ csr,
    const float* __restrict__ dis, const unsigned short* __restrict__ h,
    const float* __restrict__ bias, float* __restrict__ out, int Nn) {
    int n = (blockIdx.x * 256 + threadIdx.x) >> 6;
    int lane = threadIdx.x & 63;
    if (n >= Nn) return;
    const int hh = lane >> 5;
    const int l = lane & 31;
    int beg = rp[n], end = rp[n + 1];
    float4 a0 = {0,0,0,0}, a1 = {0,0,0,0}, a2 = {0,0,0,0}, a3 = {0,0,0,0};
    auto P = [&](int e, float4& a) {
        int s = csr[e];
        float w = dis[s];
        ushort4 v = *(const ushort4*)&h[(size_t)s * 128 + l * 4];
        a.x = fmaf(w, bf2f(v.x), a.x); a.y = fmaf(w, bf2f(v.y), a.y);
        a.z = fmaf(w, bf2f(v.z), a.z); a.w = fmaf(w, bf2f(v.w), a.w);
    };
    int j = beg + hh;
    for (; j + 6 < end; j += 8) { P(j, a0); P(j + 2, a1); P(j + 4, a2); P(j + 6, a3); }
    for (; j < end; j += 2) P(j, a0);
    float4 acc;
    acc.x = (a0.x + a1.x) + (a2.x + a3.x);
    acc.y = (a0.y + a1.y) + (a2.y + a3.y);
    acc.z = (a0.z + a1.z) + (a2.z + a3.z);
    acc.w = (a0.w + a1.w) + (a2.w + a3.w);
    acc.x += __shfl_xor(acc.x, 32);
    acc.y += __shfl_xor(acc.y, 32);
    acc.z += __shfl_xor(acc.z, 32);
    acc.w += __shfl_xor(acc.w, 32);
    float dn = dis[n];
    ushort4 hv = *(const ushort4*)&h[(size_t)n * 128 + l * 4];
    float4 b4 = *(const float4*)&bias[l * 4];
    float4 o;
    o.x = fmaxf(dn * (acc.x + dn * bf2f(hv.x)) + b4.x, 0.f);
    o.y = fmaxf(dn * (acc.y + dn * bf2f(hv.y)) + b4.y, 0.f);
    o.z = fmaxf(dn * (acc.z + dn * bf2f(hv.z)) + b4.z, 0.f);
    o.w = fmaxf(dn * (acc.w + dn * bf2f(hv.w)) + b4.w, 0.f);
    if (hh == 0) *(float4*)&out[(size_t)n * 128 + l * 4] = o;
}

// gather for F=64 (bf16 h): quarter-wave per edge, 8 rows in flight.
__global__ __launch_bounds__(256) void gather64(
    const int* __restrict__ rp, const int* __restrict__ csr,
    const float* __restrict__ dis, const unsigned short* __restrict__ h,
    const float* __restrict__ bias, float* __restrict__ out, int Nn) {
    int n = (blockIdx.x * 256 + threadIdx.x) >> 6;
    int lane = threadIdx.x & 63;
    if (n >= Nn) return;
    const int q = lane >> 4;
    const int l = lane & 15;
    int beg = rp[n], end = rp[n + 1];
    float4 a0 = {0,0,0,0}, a1 = {0,0,0,0};
    auto P = [&](int e, float4& a) {
        int s = csr[e];
        float w = dis[s];
        ushort4 v = *(const ushort4*)&h[(size_t)s * 64 + l * 4];
        a.x = fmaf(w, bf2f(v.x), a.x); a.y = fmaf(w, bf2f(v.y), a.y);
        a.z = fmaf(w, bf2f(v.z), a.z); a.w = fmaf(w, bf2f(v.w), a.w);
    };
    int j = beg + q;
    for (; j + 4 < end; j += 8) { P(j, a0); P(j + 4, a1); }
    for (; j < end; j += 4) P(j, a0);
    float4 acc;
    acc.x = a0.x + a1.x; acc.y = a0.y + a1.y;
    acc.z = a0.z + a1.z; acc.w = a0.w + a1.w;
    acc.x += __shfl_xor(acc.x, 16); acc.x += __shfl_xor(acc.x, 32);
    acc.y += __shfl_xor(acc.y, 16); acc.y += __shfl_xor(acc.y, 32);
    acc.z += __shfl_xor(acc.z, 16); acc.z += __shfl_xor(acc.z, 32);
    acc.w += __shfl_xor(acc.w, 16); acc.w += __shfl_xor(acc.w, 32);
    float dn = dis[n];
    ushort4 hv = *(const ushort4*)&h[(size_t)n * 64 + l * 4];
    float4 b4 = *(const float4*)&bias[l * 4];
    float4 o;
    o.x = dn * (acc.x + dn * bf2f(hv.x)) + b4.x;
    o.y = dn * (acc.y + dn * bf2f(hv.y)) + b4.y;
    o.z = dn * (acc.z + dn * bf2f(hv.z)) + b4.z;
    o.w = dn * (acc.w + dn * bf2f(hv.w)) + b4.w;
    if (q == 0) *(float4*)&out[(size_t)n * 64 + l * 4] = o;
}

extern "C" void kernel_launch(void* const* d_in, const int* in_sizes, int n_in,
                              void* d_out, int out_size, void* d_ws, size_t ws_size,
                              hipStream_t stream) {
    const float* x  = (const float*)d_in[0];
    const int*   ei = (const int*)d_in[1];
    const float* W1 = (const float*)d_in[2];
    const float* b1 = (const float*)d_in[3];
    const float* W2 = (const float*)d_in[4];
    const float* b2 = (const float*)d_in[5];

    const int IN = 500, H = 128, OUT = 64;
    const int Nn = in_sizes[0] / IN;     // 50000
    const int E  = in_sizes[1] / 2;      // 800000
    const int* src  = ei;
    const int* dstp = ei + E;

    const int Npad = ((Nn + 63) / 64) * 64;
    const int nb   = (Nn + 255) / 256;
    const int ngemm = (Nn + 63) / 64;    // 782
    const int ncsr  = (E + 255) / 256;   // 3125

    // workspace layout (int units)
    int*   degdis  = (int*)d_ws;                 // N: int deg -> float dis in place
    int*   rp      = degdis + Npad;              // N+1
    int*   bsum    = rp + Npad + 64;             // 1024
    int*   boff    = bsum + 1024;                // 1024
    int*   cursor  = boff + 1024;                // N
    int*   csr_src = cursor + Npad;              // E
    unsigned short* I1 = (unsigned short*)(csr_src + ((E + 63) / 64) * 64);  // 16 x 16KB
    unsigned short* I2 = I1 + 16 * 8192;         // 4 x 8KB
    unsigned short* h1u = I2 + 4 * 4096;         // Npad x 128 bf16
    float* agg1    = (float*)(h1u + (size_t)Npad * H);  // Npad x 128 f32
    unsigned short* h2u = h1u;                   // reuse after layer-1 gather
    float* dis     = (float*)degdis;
    float* out     = (float*)d_out;

    // ---- degree zero + B-image prep ----
    prep_imgs<<<(Nn + 255) / 256, 256, 0, stream>>>(W1, W2, I1, I2, degdis, Nn);
    deg_accum_i<<<ncsr, 256, 0, stream>>>(dstp, degdis, E);
    scan_part<<<nb, 256, 0, stream>>>(degdis, bsum, Nn);
    scan_top<<<1, 1024, 0, stream>>>(bsum, nb, boff, rp, Nn);
    scan_final<<<nb, 256, 0, stream>>>(degdis, boff, rp, cursor, Nn);

    // ---- FAT: gemm1 || csr_fill ----
    fat_gemm_csr<128, 16, 15><<<ngemm * 5, 256, 0, stream>>>(
        x, (const unsigned char*)I1, h1u, Nn, IN,
        src, dstp, cursor, csr_src, E, ngemm, ncsr);

    gather128<<<(Nn + 3) / 4, 256, 0, stream>>>(rp, csr_src, dis, h1u, b1, agg1, Nn);

    // ---- layer 2 ----
    gemm_glds<64, 4, 4><<<ngemm, 256, 0, stream>>>(
        agg1, (const unsigned char*)I2, h2u, Nn, H);
    gather64<<<(Nn + 3) / 4, 256, 0, stream>>>(rp, csr_src, dis, h2u, b2, out, Nn);
}